// Round 11
// baseline (218.695 us; speedup 1.0000x reference)
//
#include <hip/hip_runtime.h>

// Capsule dynamic routing — R7 o-on-waves map + w tile in LDS (broadcast reads).
// u_i:(B,N,DI) f32, w:(1,N,NO,DI,DE) f32, bias:(N,NO,1) f32, r=3.
// Identity: logits_r = u_ji . vsum (vsum = running sum of v; u_ji includes
// bias so the bias term folds in automatically).
// R10 finding: pass-1 (no softmax/barrier) == pass-2/3 time -> limiter is the
// scalar w-load stream (s_load forces lgkmcnt(0), unpipelineable). Fix: stage
// the 40 KB w tile to LDS once; in-loop w reads are wave-uniform ds_read
// (HW broadcast, in-order lgkmcnt -> compiler pipelines). u stays global
// (vmcnt, separate counter). Block = 5 waves x 64 lanes; wave wv owns
// o{2wv,2wv+1}; lane = b. Softmax via double-buffered LDS xchg, 1 barrier/n.

#define B    256
#define N    1152
#define NO   10
#define DI   8
#define DE   16
#define NTILE   8
#define NTILES  144    // N / NTILE
#define BG      64     // b per block (= lanes per wave)
#define BGS     4      // B / BG
#define THREADS 320    // 5 waves
#define WFLT    (NO * DI * DE)         // 1280 floats per n
#define WTILE   (NTILE * WFLT)         // 10240 floats = 40 KB

// ws layout (floats) — 23.76 MB (proven size)
#define SP_OFF 0
#define SP_SZ  (NTILES * B * NO * DE)   // 5,898,240
#define VS_OFF (SP_OFF + SP_SZ)
#define VS_SZ  (B * NO * DE)            // 40,960

// ---------------------------------------------------------------------------
// Routing pass. Grid: (144 n-tiles, 4 b-groups) x 320 threads.
// ---------------------------------------------------------------------------
__global__ __launch_bounds__(THREADS, 3)
void routing_kernel(const float* __restrict__ u,
                    const float* __restrict__ w,
                    const float* __restrict__ bias,
                    const float* __restrict__ vsum,
                    float* __restrict__ s_part,
                    const int has_v) {
    __shared__ __align__(16) float lds_w[WTILE];   // 40 KB
    __shared__ float lgx[2][NO][BG];               // 5 KB logit exchange
    const int tid  = threadIdx.x;
    const int lane = tid & 63;
    const int wv   = __builtin_amdgcn_readfirstlane(tid >> 6);  // 0..4 uniform
    const int o0   = wv * 2;
    const int b    = blockIdx.y * BG + lane;
    const int n0   = blockIdx.x * NTILE;

    // --- stage w tile: 2560 float4, coalesced, 8 per thread ---
    {
        const float4* src = (const float4*)(w + (size_t)n0 * WFLT);
        float4* dst = (float4*)lds_w;
#pragma unroll
        for (int j = 0; j < 8; ++j)
            dst[tid + j * THREADS] = src[tid + j * THREADS];
    }

    // vsum fragment for this thread's (b, o0..o0+1), full e — loop-invariant
    float4 vv[2][4];
#pragma unroll
    for (int oi = 0; oi < 2; ++oi)
#pragma unroll
        for (int eq = 0; eq < 4; ++eq)
            vv[oi][eq] = make_float4(0.f, 0.f, 0.f, 0.f);
    if (has_v) {
#pragma unroll
        for (int oi = 0; oi < 2; ++oi)
#pragma unroll
            for (int eq = 0; eq < 4; ++eq)
                vv[oi][eq] = *(const float4*)(vsum + ((size_t)b * NO + o0 + oi) * DE + eq * 4);
    }

    float4 acc[2][4];
#pragma unroll
    for (int oi = 0; oi < 2; ++oi)
#pragma unroll
        for (int eq = 0; eq < 4; ++eq)
            acc[oi][eq] = make_float4(0.f, 0.f, 0.f, 0.f);

    __syncthreads();   // w tile staged

    for (int i = 0; i < NTILE; ++i) {
        const int n = n0 + i;

        // u row for this b from global (vmcnt — pipelines independently)
        const float* up = u + ((size_t)b * N + n) * DI;
        const float4 u0 = *(const float4*)up;
        const float4 u1 = *(const float4*)(up + 4);
        const float ur[DI] = {u0.x, u0.y, u0.z, u0.w, u1.x, u1.y, u1.z, u1.w};

        // u_ji for (o0, o0+1), all 16 e — w from LDS, wave-uniform broadcast
        const float* wp = lds_w + i * WFLT + o0 * (DI * DE);
        float4 uji[2][4];
#pragma unroll
        for (int oi = 0; oi < 2; ++oi) {
            const float bv = bias[n * NO + o0 + oi];
#pragma unroll
            for (int eq = 0; eq < 4; ++eq)
                uji[oi][eq] = make_float4(bv, bv, bv, bv);
#pragma unroll
            for (int d = 0; d < DI; ++d) {
                const float* wrow = wp + oi * (DI * DE) + d * DE;
#pragma unroll
                for (int eq = 0; eq < 4; ++eq) {
                    const float4 w4 = *(const float4*)(wrow + eq * 4);
                    uji[oi][eq].x += ur[d] * w4.x;
                    uji[oi][eq].y += ur[d] * w4.y;
                    uji[oi][eq].z += ur[d] * w4.z;
                    uji[oi][eq].w += ur[d] * w4.w;
                }
            }
        }

        float c[2];
        if (has_v) {
            // logits: full-e dot in-thread; exchange via double-buffered LDS
            const int buf = i & 1;
#pragma unroll
            for (int oi = 0; oi < 2; ++oi) {
                float lg = 0.f;
#pragma unroll
                for (int eq = 0; eq < 4; ++eq)
                    lg += uji[oi][eq].x * vv[oi][eq].x + uji[oi][eq].y * vv[oi][eq].y
                        + uji[oi][eq].z * vv[oi][eq].z + uji[oi][eq].w * vv[oi][eq].w;
                lgx[buf][o0 + oi][lane] = lg;
            }
            __syncthreads();   // single barrier; buffer parity protects reads
            float l[NO];
#pragma unroll
            for (int o = 0; o < NO; ++o) l[o] = lgx[buf][o][lane];

            float m = l[0];
#pragma unroll
            for (int o = 1; o < NO; ++o) m = fmaxf(m, l[o]);
            float sum = 0.f;
#pragma unroll
            for (int o = 0; o < NO; ++o) { l[o] = __expf(l[o] - m); sum += l[o]; }
            const float inv = 1.f / sum;
            c[0] = l[o0] * inv;
            c[1] = l[o0 + 1] * inv;
        } else {
            c[0] = 0.1f; c[1] = 0.1f;   // softmax of zeros
        }

#pragma unroll
        for (int oi = 0; oi < 2; ++oi)
#pragma unroll
            for (int eq = 0; eq < 4; ++eq) {
                acc[oi][eq].x += c[oi] * uji[oi][eq].x;
                acc[oi][eq].y += c[oi] * uji[oi][eq].y;
                acc[oi][eq].z += c[oi] * uji[oi][eq].z;
                acc[oi][eq].w += c[oi] * uji[oi][eq].w;
            }
    }

    // s_part[tile][b][o][e]
    float* sp = s_part + (((size_t)blockIdx.x * B + b) * NO + o0) * DE;
#pragma unroll
    for (int oi = 0; oi < 2; ++oi)
#pragma unroll
        for (int eq = 0; eq < 4; ++eq)
            *(float4*)(sp + oi * DE + eq * 4) = acc[oi][eq];
}

// ---------------------------------------------------------------------------
// Squash: s = sum_tiles s_part; v = ||s||/(1+||s||^2)*s; out = v; vsum += v.
// Grid 160 blocks x 256 thr. Block owns 64 consecutive f4 (=256 floats).
// Wave q (tid>>6) sums tiles q*36..q*36+35 with lanes = consecutive f4
// (fully coalesced 1 KB/wave loads); 4-wave combine via LDS; wave 0 does
// the norm (lanes 4k..4k+3 = eq 0..3 of one (b,o)) and writes out/vsum.
// ---------------------------------------------------------------------------
__global__ __launch_bounds__(256)
void squash_kernel(const float* __restrict__ s_part,
                   float* __restrict__ vsum,
                   float* __restrict__ out,
                   const int accum) {
    __shared__ __align__(16) float4 part[4][64];
    const int tid  = threadIdx.x;
    const int lane = tid & 63;
    const int q    = tid >> 6;              // wave id = tile quarter
    const int f4   = blockIdx.x * 64 + lane;  // global float4 index, <10240

    const float4* sp = (const float4*)s_part + (size_t)(q * 36) * (B * NO * DE / 4) + f4;
    float4 s = make_float4(0.f, 0.f, 0.f, 0.f);
#pragma unroll 12
    for (int i = 0; i < 36; ++i) {
        const float4 t = sp[(size_t)i * (B * NO * DE / 4)];
        s.x += t.x; s.y += t.y; s.z += t.z; s.w += t.w;
    }
    part[q][lane] = s;
    __syncthreads();

    if (q == 0) {
#pragma unroll
        for (int j = 1; j < 4; ++j) {
            const float4 t = part[j][lane];
            s.x += t.x; s.y += t.y; s.z += t.z; s.w += t.w;
        }
        float nsq = s.x * s.x + s.y * s.y + s.z * s.z + s.w * s.w;
        nsq += __shfl_xor(nsq, 1);
        nsq += __shfl_xor(nsq, 2);          // full ||s||^2 over the 4 eq lanes
        const float nrm   = sqrtf(nsq);
        const float scale = nrm / (1.f + nsq);
        const float4 val = make_float4(s.x * scale, s.y * scale,
                                       s.z * scale, s.w * scale);
        ((float4*)out)[f4] = val;
        float4* vp = (float4*)vsum + f4;
        if (accum) {
            const float4 old = *vp;
            *vp = make_float4(old.x + val.x, old.y + val.y,
                              old.z + val.z, old.w + val.w);
        } else {
            *vp = val;
        }
    }
}

extern "C" void kernel_launch(void* const* d_in, const int* in_sizes, int n_in,
                              void* d_out, int out_size, void* d_ws, size_t ws_size,
                              hipStream_t stream) {
    const float* u    = (const float*)d_in[0];
    const float* w    = (const float*)d_in[1];   // (N,NO,DI,DE)
    const float* bias = (const float*)d_in[2];   // (N,NO)
    // d_in[3] = r, static 3

    float* wsf    = (float*)d_ws;
    float* s_part = wsf + SP_OFF;
    float* vsum   = wsf + VS_OFF;
    float* out    = (float*)d_out;

    for (int it = 0; it < 3; ++it) {
        routing_kernel<<<dim3(NTILES, BGS), THREADS, 0, stream>>>(
            u, w, bias, vsum, s_part, it > 0);
        squash_kernel<<<(B * NO * DE / 4) / 64, 256, 0, stream>>>(
            s_part, vsum, out, it > 0);
    }
}